// Round 7
// baseline (1980.256 us; speedup 1.0000x reference)
//
#include <hip/hip_runtime.h>
#include <cstdint>
#include <cstddef>

#define BB 8
#define NN 16384
#define SS 512
#define KK 32
#define NB 512            // mega-kernel grid: 512 blocks x 256 thr = 131072 threads

__device__ __forceinline__ float fm(float a, float b){ return __fmul_rn(a,b); }
__device__ __forceinline__ float fa(float a, float b){ return __fadd_rn(a,b); }
__device__ __forceinline__ float fsb(float a, float b){ return __fsub_rn(a,b); }

// ---------------- farthest point sampling: 1 block (1024 thr) per batch ----------------
// VERBATIM R2 kernel (validated, 940us) + barrier-reset for the megakernel
// (fps precedes mega on the stream, so the reset is race-free and re-runs on
// every graph replay). R3/R4 proved multi-block fps loses to this (cross-block
// agent-scope barrier floor ~1.4us/step > whole single-block step 1.84us).
// DO NOT change launch config without re-verifying post-timing.
__global__ __launch_bounds__(1024, 4) void fps_kernel(const float* __restrict__ xyz,
                                                      float* __restrict__ nxyz,   // ws (B,S,3)
                                                      float* __restrict__ out,    // d_out (B,3,S)
                                                      unsigned* __restrict__ bar)
{
  if (blockIdx.x==0 && threadIdx.x<2){
    __hip_atomic_store(&bar[threadIdx.x], 0u, __ATOMIC_RELAXED, __HIP_MEMORY_SCOPE_AGENT);
  }
  int b = blockIdx.x;
  int t = threadIdx.x;           // 0..1023
  const float* xb = xyz + (size_t)b*3*NN;
  float px[16], py[16], pz[16], dist[16];
#pragma unroll
  for (int k=0;k<16;k++){
    int n = k*1024 + t;
    px[k]=xb[n]; py[k]=xb[NN+n]; pz[k]=xb[2*NN+n];
    dist[k]=1e10f;
  }
  // Pin point coords in registers (block rematerialization-as-reload).
#pragma unroll
  for (int k=0;k<16;k++){
    asm volatile("" : "+v"(px[k]), "+v"(py[k]), "+v"(pz[k]));
  }
  __shared__ unsigned long long redk[2][16];
  int wid = t >> 6, lane = t & 63;
  float cx = xb[0], cy = xb[NN], cz = xb[2*NN];
  for (int step=0; step<SS; ++step){
    if (t==0){
      float* nx = nxyz + ((size_t)b*SS + step)*3;
      nx[0]=cx; nx[1]=cy; nx[2]=cz;
      float* ox = out + (size_t)b*3*SS;
      ox[step]=cx; ox[SS+step]=cy; ox[2*SS+step]=cz;
    }
    float bv = -1.0f; int bk = 0;
#pragma unroll
    for (int k=0;k<16;k++){
      float dx=fsb(px[k],cx), dy=fsb(py[k],cy), dz=fsb(pz[k],cz);
      float d = fa(fa(fm(dx,dx),fm(dy,dy)),fm(dz,dz));
      float dk = fminf(dist[k], d);
      dist[k]=dk;
      // strict > keeps earliest k => smallest index for this thread
      if (dk > bv){ bv=dk; bk=k; }
    }
    int bi = (bk<<10) | t;
    unsigned long long key = ((unsigned long long)__float_as_uint(bv) << 32)
                           | (unsigned)(16384 - bi);
    // wave(64) butterfly max on packed key
#pragma unroll
    for (int off=1; off<64; off<<=1){
      unsigned long long ok = __shfl_xor(key, off);
      if (ok > key) key = ok;
    }
    int par = step & 1;
    if (lane==0) redk[par][wid] = key;
    __syncthreads();
    // every lane reads one of the 16 candidates (4-way same-address broadcast),
    // then 4-stage butterfly within each group of 16 -> all 64 lanes converge
    unsigned long long k2 = redk[par][lane & 15];
#pragma unroll
    for (int off=1; off<16; off<<=1){
      unsigned long long ok = __shfl_xor(k2, off);
      if (ok > k2) k2 = ok;
    }
    int i = 16384 - (int)(unsigned)(k2 & 0xFFFFFFFFull);
    cx = xb[i]; cy = xb[NN+i]; cz = xb[2*NN+i];
  }
}

// ---------------- device-scope grid barrier (R3/R4 lessons applied) ----------------
// One atomic arrival per block; ONE wave per block polls the flag with
// agent-scope acquire loads (512 pollers total -- R4 proved this level of
// polling is contention-free); release/acquire fences give cross-XCD
// visibility of the phase's writes. Co-residency: 512 blocks x 256 thr =
// 131072 threads vs 524288 slots, VGPR<=256 at launch_bounds(256,2) -- 4x
// capacity margin, all blocks resident.
__device__ __forceinline__ void gridbar(unsigned* __restrict__ bar, unsigned phase){
  __syncthreads();
  if (threadIdx.x == 0){
    __builtin_amdgcn_fence(__ATOMIC_RELEASE, "agent");
    unsigned old = __hip_atomic_fetch_add(&bar[0], 1u, __ATOMIC_ACQ_REL, __HIP_MEMORY_SCOPE_AGENT);
    if (old == (unsigned)(NB-1)){
      __hip_atomic_store(&bar[0], 0u, __ATOMIC_RELAXED, __HIP_MEMORY_SCOPE_AGENT);
      __hip_atomic_store(&bar[1], phase, __ATOMIC_RELEASE, __HIP_MEMORY_SCOPE_AGENT);
    }
  }
  if (threadIdx.x < 64){
    while (__hip_atomic_load(&bar[1], __ATOMIC_ACQUIRE, __HIP_MEMORY_SCOPE_AGENT) < phase){
      __builtin_amdgcn_s_sleep(2);
    }
  }
  __syncthreads();
  __builtin_amdgcn_fence(__ATOMIC_ACQUIRE, "agent");
}

// ---------------- phase bodies: byte-identical math to the R6 kernels ----------------

__device__ __forceinline__ void ballq_one(const float* __restrict__ xyz,
                                          const float* __restrict__ nxyz,
                                          int* __restrict__ gidx, int wv){
  int lane = threadIdx.x & 63;
  int b = wv >> 9; int s = wv & (SS-1);
  const float* nx3 = nxyz + ((size_t)b*SS + s)*3;
  float nx=nx3[0], ny=nx3[1], nz=nx3[2];
  float cn = fa(fa(fm(nx,nx),fm(ny,ny)),fm(nz,nz));
  const float* xb = xyz + (size_t)b*3*NN;
  const float R2 = (float)(0.2*0.2);   // f64 product rounded once to f32
  int* g = gidx + ((size_t)b*SS + s)*KK;
  int cnt = 0; int first_idx = 0;
  for (int base=0; base<NN; base+=64){
    int n = base + lane;
    float x=xb[n], y=xb[NN+n], z=xb[2*NN+n];
    float sq = fa(fa(fm(x,x),fm(y,y)),fm(z,z));      // == old sqn[n], bit-exact
    float dot = fa(fa(fm(nx,x),fm(ny,y)),fm(nz,z));
    float sqd = fsb(fa(cn, sq), fm(2.0f, dot));
    bool inb = !(sqd > R2);
    unsigned long long m = __ballot(inb);
    if (m){
      if (cnt==0) first_idx = base + __builtin_ctzll(m);
      int pre = __popcll(m & ((1ull<<lane)-1ull));
      int slot = cnt + pre;
      if (inb && slot < KK) g[slot] = n;
      cnt += __popcll(m);
      if (cnt >= KK) break;
    }
  }
  if (cnt < KK && lane >= cnt && lane < KK) g[lane] = first_idx;
}

__device__ __forceinline__ void stats_one(const float* __restrict__ y, int C,
                                          double* __restrict__ psum, int vb){
  int o = vb >> 3; int b = vb & 7;
  int t = threadIdx.x;
  const float4* p = (const float4*)(y + ((size_t)b*C + o)*KK*SS);
  double s1=0.0, s2=0.0;
#pragma unroll
  for (int i=0;i<16;i++){
    float4 v = p[t + i*256];
    double x0=v.x, x1=v.y, x2=v.z, x3=v.w;
    s1 += x0+x1; s1 += x2+x3;
    s2 += x0*x0 + x1*x1;
    s2 += x2*x2 + x3*x3;
  }
#pragma unroll
  for (int off=32; off>=1; off>>=1){
    s1 += __shfl_down(s1, off);
    s2 += __shfl_down(s2, off);
  }
  __shared__ double l1[4], l2[4];
  int wid = t>>6;
  if ((t&63)==0){ l1[wid]=s1; l2[wid]=s2; }
  __syncthreads();
  if (t==0){
    double t1=l1[0]+l1[1]+l1[2]+l1[3];
    double t2=l2[0]+l2[1]+l2[2]+l2[3];
    psum[(o*8+b)*2+0]=t1;
    psum[(o*8+b)*2+1]=t2;
  }
  __syncthreads();   // l1/l2 are reused by a second call (stats2) -- keep ordered
}

// BN finalize: identical math/summation order to the original stats_fin_kernel,
// so a/c are bit-identical f64->f32 results.
template<int C>
__device__ __forceinline__ void bn_finalize_lds(const double* __restrict__ psum,
                                                const float* __restrict__ gamma,
                                                const float* __restrict__ beta,
                                                float* sa, float* sc)
{
  int o = threadIdx.x;
  if (o < C){
    double t1=0.0, t2=0.0;
#pragma unroll
    for (int b=0;b<8;b++){ t1 += psum[(o*8+b)*2+0]; t2 += psum[(o*8+b)*2+1]; }
    double n = (double)BB*KK*SS;
    double m = t1/n;
    double var = t2/n - m*m;
    double inv = 1.0/sqrt(var + 1e-5);
    float s = (float)((double)gamma[o]*inv);
    sa[o]=s; sc[o]=(float)((double)beta[o] - m*(double)s);
  }
  __syncthreads();
}

template<int CIN, int COUT>
__device__ __forceinline__ void mlp_one(const float* __restrict__ yin,
                                        const float* __restrict__ w,
                                        const float* __restrict__ bias,
                                        const double* __restrict__ psum,
                                        const float* __restrict__ gamma,
                                        const float* __restrict__ beta,
                                        float* __restrict__ yout)
{
  __shared__ float sa[CIN], sc[CIN];
  bn_finalize_lds<CIN>(psum, gamma, beta, sa, sc);
  int gid = blockIdx.x*blockDim.x + threadIdx.x; // B*K*S
  int b = gid / (KK*SS);
  int r = gid % (KK*SS);
  const float* pin = yin + (size_t)b*CIN*KK*SS + r;
  float x[CIN];
#pragma unroll
  for (int ci=0;ci<CIN;ci++) x[ci] = fmaxf(fmaf(pin[(size_t)ci*KK*SS], sa[ci], sc[ci]), 0.0f);
  float* po = yout + (size_t)b*COUT*KK*SS + r;
  for (int o=0;o<COUT;o++){
    float acc = bias[o];
#pragma unroll
    for (int ci=0;ci<CIN;ci++) acc += x[ci]*w[o*CIN+ci];
    po[(size_t)o*KK*SS] = acc;
  }
  __syncthreads();   // sa/sc reuse safety across phases
}

// ---------------- megakernel: ballq -> mlp0 -> stats0 -> mlp1 -> stats1 ->
// mlp2 -> stats2 -> final, separated by 7 in-kernel grid barriers ----------------
__global__ __launch_bounds__(256, 2) void mega_kernel(const float* __restrict__ xyz,
                            const float* __restrict__ pts,
                            const float* __restrict__ nxyz,
                            int* __restrict__ gidx,
                            const float* __restrict__ w0, const float* __restrict__ b0,
                            const float* __restrict__ g0, const float* __restrict__ be0,
                            const float* __restrict__ w1, const float* __restrict__ b1,
                            const float* __restrict__ g1, const float* __restrict__ be1,
                            const float* __restrict__ w2, const float* __restrict__ b2,
                            const float* __restrict__ g2, const float* __restrict__ be2,
                            float* __restrict__ y0, float* __restrict__ y1, float* __restrict__ y2,
                            double* __restrict__ ps0, double* __restrict__ ps1, double* __restrict__ ps2,
                            float* __restrict__ out,      // d_out + B*3*S
                            unsigned* __restrict__ bar)
{
  const int bid = blockIdx.x, tid = threadIdx.x;

  // ---- P0: ball query (2 centroids per wave: 512 blk x 4 waves x 2 = 4096) ----
  {
    int wv0 = (bid*4 + (tid>>6))*2;
    ballq_one(xyz, nxyz, gidx, wv0);
    ballq_one(xyz, nxyz, gidx, wv0+1);
  }
  gridbar(bar, 1);

  // ---- P1: mlp0 (gather + concat + conv 6->64) ----
  {
    int gid = bid*256 + tid;  // B*K*S
    int b = gid / (KK*SS);
    int r = gid % (KK*SS);
    int k = r / SS; int s = r % SS;
    int idx = gidx[((size_t)b*SS + s)*KK + k];
    const float* pb = pts + (size_t)b*3*NN;
    const float* xb = xyz + (size_t)b*3*NN;
    const float* nx3 = nxyz + ((size_t)b*SS + s)*3;
    float in[6];
    in[0]=pb[idx]; in[1]=pb[NN+idx]; in[2]=pb[2*NN+idx];
    in[3]=xb[idx]-nx3[0]; in[4]=xb[NN+idx]-nx3[1]; in[5]=xb[2*NN+idx]-nx3[2];
    float* po = y0 + (size_t)b*64*KK*SS + r;
    for (int o=0;o<64;o++){
      float acc = b0[o];
#pragma unroll
      for (int c=0;c<6;c++) acc += in[c]*w0[o*6+c];
      po[(size_t)o*KK*SS] = acc;
    }
  }
  gridbar(bar, 2);

  // ---- P2: stats over y0 (512 (o,b) pairs, one per block) ----
  stats_one(y0, 64, ps0, bid);
  gridbar(bar, 3);

  // ---- P3: mlp1 (bn+relu fused input, conv 64->64) ----
  mlp_one<64,64>(y0, w1, b1, ps0, g0, be0, y1);
  gridbar(bar, 4);

  // ---- P4: stats over y1 ----
  stats_one(y1, 64, ps1, bid);
  gridbar(bar, 5);

  // ---- P5: mlp2 (conv 64->128) ----
  mlp_one<64,128>(y1, w2, b2, ps1, g1, be1, y2);
  gridbar(bar, 6);

  // ---- P6: stats over y2 (1024 pairs, 2 per block) ----
  stats_one(y2, 128, ps2, bid);
  stats_one(y2, 128, ps2, bid + NB);
  gridbar(bar, 7);

  // ---- P7: final bn+relu+max over K ----
  {
    __shared__ float sa[128], sc[128];
    bn_finalize_lds<128>(ps2, g2, be2, sa, sc);
    int gid = bid*256 + tid;  // B*128*(S/4)
    int b = gid / (128*128);
    int r = gid % (128*128);
    int o = r >> 7; int s4 = (r & 127);
    const float4* p = (const float4*)(y2 + ((size_t)b*128 + o)*KK*SS) + s4;
    float scv=sa[o], sh=sc[o];
    float m0=0.f,m1=0.f,m2=0.f,m3=0.f;  // relu outputs >= 0, 32 values exist
#pragma unroll
    for (int k=0;k<KK;k++){
      float4 v = p[k*(SS/4)];
      m0 = fmaxf(m0, fmaxf(fmaf(v.x, scv, sh), 0.0f));
      m1 = fmaxf(m1, fmaxf(fmaf(v.y, scv, sh), 0.0f));
      m2 = fmaxf(m2, fmaxf(fmaf(v.z, scv, sh), 0.0f));
      m3 = fmaxf(m3, fmaxf(fmaf(v.w, scv, sh), 0.0f));
    }
    float4* po = (float4*)(out + ((size_t)b*128 + o)*SS) + s4;
    *po = make_float4(m0,m1,m2,m3);
  }
}

extern "C" void kernel_launch(void* const* d_in, const int* in_sizes, int n_in,
                              void* d_out, int out_size, void* d_ws, size_t ws_size,
                              hipStream_t stream)
{
  const float* xyz = (const float*)d_in[0];
  const float* pts = (const float*)d_in[1];
  const float* w0  = (const float*)d_in[2];
  const float* b0  = (const float*)d_in[3];
  const float* g0  = (const float*)d_in[4];
  const float* be0 = (const float*)d_in[5];
  const float* w1  = (const float*)d_in[6];
  const float* b1  = (const float*)d_in[7];
  const float* g1  = (const float*)d_in[8];
  const float* be1 = (const float*)d_in[9];
  const float* w2  = (const float*)d_in[10];
  const float* b2  = (const float*)d_in[11];
  const float* g2  = (const float*)d_in[12];
  const float* be2 = (const float*)d_in[13];
  float* out = (float*)d_out;

  char* ws = (char*)d_ws;
  float*  nxyz = (float*) (ws + 524288);     // B*S*3 f32        = 49152 B
  int*    gidx = (int*)   (ws + 573440);     // B*S*K i32        = 524288 B
  double* ps0  = (double*)(ws + 1099776);    // 64*8*2 f64  = 8192 B
  double* ps1  = (double*)(ws + 1107968);    // 64*8*2 f64  = 8192 B
  double* ps2  = (double*)(ws + 1116160);    // 128*8*2 f64 = 16384 B
  unsigned* bar = (unsigned*)(ws + 1132544); // 2 x u32 (cnt, flag)
  // y1 at 4MiB (33.5MB), y2 at 40MiB (67MB), y0 at 76MiB (33.5MB)
  float* y1 = (float*)(ws + 4194304);
  float* y2 = (float*)(ws + 41943040);
  float* y0 = (float*)(ws + 79691776);
  (void)ws_size; (void)in_sizes; (void)n_in; (void)out_size;

  fps_kernel<<<dim3(BB), dim3(1024), 0, stream>>>(xyz, nxyz, out, bar);
  mega_kernel<<<dim3(NB), dim3(256), 0, stream>>>(xyz, pts, nxyz, gidx,
      w0, b0, g0, be0, w1, b1, g1, be1, w2, b2, g2, be2,
      y0, y1, y2, ps0, ps1, ps2, out + BB*3*SS, bar);
}

// Round 8
// 1833.446 us; speedup vs baseline: 1.0801x; 1.0801x over previous
//
#include <hip/hip_runtime.h>
#include <cstdint>
#include <cstddef>

#define BB 8
#define NN 16384
#define SS 512
#define KK 32
#define NBK 512           // mega grid: 512 blocks x 256 thr; 2 blocks/CU -> all co-resident (R7-proven)

__device__ __forceinline__ float fm(float a, float b){ return __fmul_rn(a,b); }
__device__ __forceinline__ float fa(float a, float b){ return __fadd_rn(a,b); }
__device__ __forceinline__ float fsb(float a, float b){ return __fsub_rn(a,b); }

// ---------------- farthest point sampling: 1 block (1024 thr) per batch ----------------
// VERBATIM R2 kernel (validated, 940us) + barrier reset (fps precedes mega on
// the stream every replay -> graph-replay-safe). R3/R4: multi-block fps loses.
// DO NOT change launch config without re-verifying post-timing.
__global__ __launch_bounds__(1024, 4) void fps_kernel(const float* __restrict__ xyz,
                                                      float* __restrict__ nxyz,   // ws (B,S,3)
                                                      float* __restrict__ out,    // d_out (B,3,S)
                                                      unsigned* __restrict__ bar)
{
  if (blockIdx.x==0 && threadIdx.x<2){
    __hip_atomic_store(&bar[threadIdx.x], 0u, __ATOMIC_RELAXED, __HIP_MEMORY_SCOPE_AGENT);
  }
  int b = blockIdx.x;
  int t = threadIdx.x;           // 0..1023
  const float* xb = xyz + (size_t)b*3*NN;
  float px[16], py[16], pz[16], dist[16];
#pragma unroll
  for (int k=0;k<16;k++){
    int n = k*1024 + t;
    px[k]=xb[n]; py[k]=xb[NN+n]; pz[k]=xb[2*NN+n];
    dist[k]=1e10f;
  }
#pragma unroll
  for (int k=0;k<16;k++){
    asm volatile("" : "+v"(px[k]), "+v"(py[k]), "+v"(pz[k]));
  }
  __shared__ unsigned long long redk[2][16];
  int wid = t >> 6, lane = t & 63;
  float cx = xb[0], cy = xb[NN], cz = xb[2*NN];
  for (int step=0; step<SS; ++step){
    if (t==0){
      float* nx = nxyz + ((size_t)b*SS + step)*3;
      nx[0]=cx; nx[1]=cy; nx[2]=cz;
      float* ox = out + (size_t)b*3*SS;
      ox[step]=cx; ox[SS+step]=cy; ox[2*SS+step]=cz;
    }
    float bv = -1.0f; int bk = 0;
#pragma unroll
    for (int k=0;k<16;k++){
      float dx=fsb(px[k],cx), dy=fsb(py[k],cy), dz=fsb(pz[k],cz);
      float d = fa(fa(fm(dx,dx),fm(dy,dy)),fm(dz,dz));
      float dk = fminf(dist[k], d);
      dist[k]=dk;
      if (dk > bv){ bv=dk; bk=k; }   // strict > keeps earliest k
    }
    int bi = (bk<<10) | t;
    unsigned long long key = ((unsigned long long)__float_as_uint(bv) << 32)
                           | (unsigned)(16384 - bi);
#pragma unroll
    for (int off=1; off<64; off<<=1){
      unsigned long long ok = __shfl_xor(key, off);
      if (ok > key) key = ok;
    }
    int par = step & 1;
    if (lane==0) redk[par][wid] = key;
    __syncthreads();
    unsigned long long k2 = redk[par][lane & 15];
#pragma unroll
    for (int off=1; off<16; off<<=1){
      unsigned long long ok = __shfl_xor(k2, off);
      if (ok > k2) k2 = ok;
    }
    int i = 16384 - (int)(unsigned)(k2 & 0xFFFFFFFFull);
    cx = xb[i]; cy = xb[NN+i]; cz = xb[2*NN+i];
  }
}

// ---------------- grid barrier (verbatim R7 -- validated & co-residency-proven) ----------------
__device__ __forceinline__ void gridbar(unsigned* __restrict__ bar, unsigned phase){
  __syncthreads();
  if (threadIdx.x == 0){
    __builtin_amdgcn_fence(__ATOMIC_RELEASE, "agent");
    unsigned old = __hip_atomic_fetch_add(&bar[0], 1u, __ATOMIC_ACQ_REL, __HIP_MEMORY_SCOPE_AGENT);
    if (old == (unsigned)(NBK-1)){
      __hip_atomic_store(&bar[0], 0u, __ATOMIC_RELAXED, __HIP_MEMORY_SCOPE_AGENT);
      __hip_atomic_store(&bar[1], phase, __ATOMIC_RELEASE, __HIP_MEMORY_SCOPE_AGENT);
    }
  }
  if (threadIdx.x < 64){
    while (__hip_atomic_load(&bar[1], __ATOMIC_ACQUIRE, __HIP_MEMORY_SCOPE_AGENT) < phase){
      __builtin_amdgcn_s_sleep(2);
    }
  }
  __syncthreads();
  __builtin_amdgcn_fence(__ATOMIC_ACQUIRE, "agent");
}

// ---------------- ball query into LDS row (math verbatim R6 ballq) ----------------
__device__ __forceinline__ void ballq_lds(const float* __restrict__ xb,
                                          const float* __restrict__ nx3,
                                          int* __restrict__ grow){
  int lane = threadIdx.x & 63;
  float nx=nx3[0], ny=nx3[1], nz=nx3[2];
  float cn = fa(fa(fm(nx,nx),fm(ny,ny)),fm(nz,nz));
  const float R2 = (float)(0.2*0.2);   // f64 product rounded once to f32
  int cnt = 0; int first_idx = 0;
  for (int base=0; base<NN; base+=64){
    int n = base + lane;
    float x=xb[n], y=xb[NN+n], z=xb[2*NN+n];
    float sq = fa(fa(fm(x,x),fm(y,y)),fm(z,z));      // == old sqn[n], bit-exact
    float dot = fa(fa(fm(nx,x),fm(ny,y)),fm(nz,z));
    float sqd = fsb(fa(cn, sq), fm(2.0f, dot));
    bool inb = !(sqd > R2);
    unsigned long long m = __ballot(inb);
    if (m){
      if (cnt==0) first_idx = base + __builtin_ctzll(m);
      int pre = __popcll(m & ((1ull<<lane)-1ull));
      int slot = cnt + pre;
      if (inb && slot < KK) grow[slot] = n;
      cnt += __popcll(m);
      if (cnt >= KK) break;
    }
  }
  if (cnt < KK && lane >= cnt && lane < KK) grow[lane] = first_idx;
}

// ---------------- per-channel stats butterfly: deterministic f64 tree ----------------
// (summation ORDER differs from the old (o,b)-partition kernels; f64 carries
// 29 extra bits past f32, so the final f32 a/c are expected bit-identical.)
template<int C>
__device__ __forceinline__ void stat_bfly(double v1, double v2, int o, double* __restrict__ redw){
#pragma unroll
  for (int off=1; off<64; off<<=1){ v1 += __shfl_xor(v1, off); v2 += __shfl_xor(v2, off); }
  if ((threadIdx.x & 63) == 0){
    int w = threadIdx.x >> 6;
    redw[(w*C + o)*2 + 0] = v1;
    redw[(w*C + o)*2 + 1] = v2;
  }
}

template<int C>
__device__ __forceinline__ void stat_emit(double* __restrict__ redw, double* __restrict__ ps, int bid){
  __syncthreads();
  int tid = threadIdx.x;
  if (tid < C){
    double t1=0.0, t2=0.0;
#pragma unroll
    for (int w=0; w<4; w++){ t1 += redw[(w*C+tid)*2]; t2 += redw[(w*C+tid)*2+1]; }
    ps[((size_t)tid*NBK + bid)*2 + 0] = t1;
    ps[((size_t)tid*NBK + bid)*2 + 1] = t2;
  }
}

// ---------------- channel reducer: 512 partials -> a/c (same f64 formula as before) ----------------
__device__ __forceinline__ void reduce_one(const double* __restrict__ ps, int ch,
                                           const float* __restrict__ gamma,
                                           const float* __restrict__ beta,
                                           float* __restrict__ ag, float* __restrict__ cg,
                                           double* __restrict__ lds8){
  int tid = threadIdx.x;
  const double* p = ps + (size_t)ch*NBK*2;
  double s1 = p[tid*2]   + p[(tid+256)*2];
  double s2 = p[tid*2+1] + p[(tid+256)*2+1];
#pragma unroll
  for (int off=1; off<64; off<<=1){ s1 += __shfl_xor(s1, off); s2 += __shfl_xor(s2, off); }
  if ((tid & 63) == 0){ lds8[(tid>>6)*2] = s1; lds8[(tid>>6)*2+1] = s2; }
  __syncthreads();
  if (tid == 0){
    double t1=0.0, t2=0.0;
#pragma unroll
    for (int w=0; w<4; w++){ t1 += lds8[w*2]; t2 += lds8[w*2+1]; }
    double n = (double)BB*KK*SS;
    double m = t1/n;
    double var = t2/n - m*m;
    double inv = 1.0/sqrt(var + 1e-5);
    float s = (float)((double)gamma[ch]*inv);
    ag[ch] = s; cg[ch] = (float)((double)beta[ch] - m*(double)s);
  }
}

// ---------------- megakernel v2: register-resident column pipeline ----------------
// Block = (batch b, 8 consecutive s) x all 32 k. Thread = one column, k-major
// (tid = si*32 + k) so final max-over-k is an intra-wave shfl. y0/y1/y2 never
// touch memory: x0/x1 live in registers; stats consume recomputed scalars.
__global__ __launch_bounds__(256, 2) void mega_kernel(const float* __restrict__ xyz,
                            const float* __restrict__ pts,
                            const float* __restrict__ nxyz,
                            const float* __restrict__ w0g, const float* __restrict__ b0g,
                            const float* __restrict__ g0, const float* __restrict__ be0,
                            const float* __restrict__ w1g, const float* __restrict__ b1g,
                            const float* __restrict__ g1, const float* __restrict__ be1,
                            const float* __restrict__ w2g, const float* __restrict__ b2g,
                            const float* __restrict__ g2, const float* __restrict__ be2,
                            double* __restrict__ ps0, double* __restrict__ ps1, double* __restrict__ ps2,
                            float* __restrict__ st,       // a0,c0,a1,c1,a2,c2
                            float* __restrict__ outf,     // d_out + B*3*S : (B,128,S)
                            unsigned* __restrict__ bar)
{
  const int bid = blockIdx.x, tid = threadIdx.x;
  const int b   = bid >> 6;            // batch
  const int s0  = (bid & 63) * 8;      // s-range start
  const int si  = tid >> 5;            // 0..7
  const int k   = tid & 31;            // 0..31 (lane-local within 32-group)
  const int w   = tid >> 6;

  __shared__ int    gl[8][KK];         // ball-query result per (s-slot)
  __shared__ double redw[4*128*2];     // per-wave per-channel stats staging (8KB)
  __shared__ float  sa[128], sc[128];  // current layer's BN scale/shift

  float* ag0 = st;       float* cg0 = st+64;
  float* ag1 = st+128;   float* cg1 = st+192;
  float* ag2 = st+256;   float* cg2 = st+384;

  const float* xb = xyz + (size_t)b*3*NN;
  const float* pb = pts + (size_t)b*3*NN;

  // ---- P0: ball query for the block's 8 (b,s) pairs (2 per wave) ----
  for (int scan=0; scan<2; ++scan){
    int p = 2*w + scan;                 // 0..7
    int s = s0 + p;
    ballq_lds(xb, nxyz + ((size_t)b*SS + s)*3, gl[p]);
  }
  __syncthreads();

  // ---- P1: gather in[6]; stats0 from recomputed y0 (dynamic o-loop) ----
  const int s = s0 + si;
  const int idx = gl[si][k];
  const float* nx3 = nxyz + ((size_t)b*SS + s)*3;
  float in[6];
  in[0]=pb[idx]; in[1]=pb[NN+idx]; in[2]=pb[2*NN+idx];
  in[3]=xb[idx]-nx3[0]; in[4]=xb[NN+idx]-nx3[1]; in[5]=xb[2*NN+idx]-nx3[2];
  for (int o=0; o<64; ++o){
    float acc = b0g[o];
#pragma unroll
    for (int c=0;c<6;c++) acc += in[c]*w0g[o*6+c];
    double v = (double)acc;
    stat_bfly<64>(v, v*v, o, redw);
  }
  stat_emit<64>(redw, ps0, bid);
  gridbar(bar, 1);
  if (bid < 64) reduce_one(ps0, bid, g0, be0, ag0, cg0, redw);
  gridbar(bar, 2);

  // ---- P3: x0 = relu-bn(y0); stats1 from recomputed y1 ----
  if (tid < 64){
    sa[tid] = __hip_atomic_load(ag0+tid, __ATOMIC_RELAXED, __HIP_MEMORY_SCOPE_AGENT);
    sc[tid] = __hip_atomic_load(cg0+tid, __ATOMIC_RELAXED, __HIP_MEMORY_SCOPE_AGENT);
  }
  __syncthreads();
  float x0[64];
#pragma unroll
  for (int ci=0; ci<64; ++ci){
    float acc = b0g[ci];
#pragma unroll
    for (int c=0;c<6;c++) acc += in[c]*w0g[ci*6+c];
    x0[ci] = fmaxf(fmaf(acc, sa[ci], sc[ci]), 0.0f);
  }
  for (int o=0; o<64; ++o){
    float acc = b1g[o];
#pragma unroll
    for (int ci=0;ci<64;ci++) acc += x0[ci]*w1g[o*64+ci];
    double v = (double)acc;
    stat_bfly<64>(v, v*v, o, redw);
  }
  stat_emit<64>(redw, ps1, bid);
  gridbar(bar, 3);
  if (bid < 64) reduce_one(ps1, bid, g1, be1, ag1, cg1, redw);
  gridbar(bar, 4);

  // ---- P5: x1 = relu-bn(y1); stats2 from recomputed y2 ----
  if (tid < 64){
    sa[tid] = __hip_atomic_load(ag1+tid, __ATOMIC_RELAXED, __HIP_MEMORY_SCOPE_AGENT);
    sc[tid] = __hip_atomic_load(cg1+tid, __ATOMIC_RELAXED, __HIP_MEMORY_SCOPE_AGENT);
  }
  __syncthreads();
  float x1[64];
#pragma unroll
  for (int ci=0; ci<64; ++ci){
    float acc = b1g[ci];
#pragma unroll
    for (int cj=0;cj<64;cj++) acc += x0[cj]*w1g[ci*64+cj];
    x1[ci] = fmaxf(fmaf(acc, sa[ci], sc[ci]), 0.0f);
  }
  for (int o=0; o<128; ++o){
    float acc = b2g[o];
#pragma unroll
    for (int ci=0;ci<64;ci++) acc += x1[ci]*w2g[o*64+ci];
    double v = (double)acc;
    stat_bfly<128>(v, v*v, o, redw);
  }
  stat_emit<128>(redw, ps2, bid);
  gridbar(bar, 5);
  if (bid < 128) reduce_one(ps2, bid, g2, be2, ag2, cg2, redw);
  gridbar(bar, 6);

  // ---- P7: final = max over k of relu-bn(recomputed y2) ----
  if (tid < 128){
    sa[tid] = __hip_atomic_load(ag2+tid, __ATOMIC_RELAXED, __HIP_MEMORY_SCOPE_AGENT);
    sc[tid] = __hip_atomic_load(cg2+tid, __ATOMIC_RELAXED, __HIP_MEMORY_SCOPE_AGENT);
  }
  __syncthreads();
  for (int o=0; o<128; ++o){
    float acc = b2g[o];
#pragma unroll
    for (int ci=0;ci<64;ci++) acc += x1[ci]*w2g[o*64+ci];
    float val = fmaxf(fmaf(acc, sa[o], sc[o]), 0.0f);   // y2 recompute == P5 value (same expr/order)
#pragma unroll
    for (int off=1; off<32; off<<=1) val = fmaxf(val, __shfl_xor(val, off)); // fmax exact-assoc
    if (k == 0) outf[((size_t)b*128 + o)*SS + s] = val;
  }
}

extern "C" void kernel_launch(void* const* d_in, const int* in_sizes, int n_in,
                              void* d_out, int out_size, void* d_ws, size_t ws_size,
                              hipStream_t stream)
{
  const float* xyz = (const float*)d_in[0];
  const float* pts = (const float*)d_in[1];
  const float* w0  = (const float*)d_in[2];
  const float* b0  = (const float*)d_in[3];
  const float* g0  = (const float*)d_in[4];
  const float* be0 = (const float*)d_in[5];
  const float* w1  = (const float*)d_in[6];
  const float* b1  = (const float*)d_in[7];
  const float* g1  = (const float*)d_in[8];
  const float* be1 = (const float*)d_in[9];
  const float* w2  = (const float*)d_in[10];
  const float* b2  = (const float*)d_in[11];
  const float* g2  = (const float*)d_in[12];
  const float* be2 = (const float*)d_in[13];
  float* out = (float*)d_out;

  char* ws = (char*)d_ws;
  float*    nxyz = (float*)   (ws + 524288);    // B*S*3 f32 = 49152 B
  float*    st   = (float*)   (ws + 1097728);   // 512 f32 (a/c per layer)
  unsigned* bar  = (unsigned*)(ws + 1132544);   // 2 x u32
  double*   ps0  = (double*)  (ws + 4194304);   // 64*512*2 f64 = 512 KB
  double*   ps1  = (double*)  (ws + 8388608);   // 64*512*2 f64 = 512 KB
  double*   ps2  = (double*)  (ws + 12582912);  // 128*512*2 f64 = 1 MB
  (void)ws_size; (void)in_sizes; (void)n_in; (void)out_size;

  fps_kernel<<<dim3(BB), dim3(1024), 0, stream>>>(xyz, nxyz, out, bar);
  mega_kernel<<<dim3(NBK), dim3(256), 0, stream>>>(xyz, pts, nxyz,
      w0, b0, g0, be0, w1, b1, g1, be1, w2, b2, g2, be2,
      ps0, ps1, ps2, st, out + BB*3*SS, bar);
}

// Round 11
// 1812.076 us; speedup vs baseline: 1.0928x; 1.0118x over previous
//
#include <hip/hip_runtime.h>
#include <cstdint>
#include <cstddef>

#define BB 8
#define NN 16384
#define SS 512
#define KK 32
#define NBK 512           // mega grid: 512 blocks x 256 thr; 2 blocks/CU co-resident (R7/R8-proven)

__device__ __forceinline__ float fm(float a, float b){ return __fmul_rn(a,b); }
__device__ __forceinline__ float fa(float a, float b){ return __fadd_rn(a,b); }
__device__ __forceinline__ float fsb(float a, float b){ return __fsub_rn(a,b); }

// ---------------- farthest point sampling: 1 block (1024 thr) per batch ----------------
// VERBATIM R2 kernel (validated, 940us) + barrier-region reset (fps precedes
// mega on the stream every replay -> graph-replay-safe; covers ALL words the
// barrier touches: bar[0]=cnt, bar[1]=flag).
__global__ __launch_bounds__(1024, 4) void fps_kernel(const float* __restrict__ xyz,
                                                      float* __restrict__ nxyz,   // ws (B,S,3)
                                                      float* __restrict__ out,    // d_out (B,3,S)
                                                      unsigned* __restrict__ bar)
{
  if (blockIdx.x==0 && threadIdx.x<256){
    __hip_atomic_store(&bar[threadIdx.x], 0u, __ATOMIC_RELAXED, __HIP_MEMORY_SCOPE_AGENT);
  }
  int b = blockIdx.x;
  int t = threadIdx.x;           // 0..1023
  const float* xb = xyz + (size_t)b*3*NN;
  float px[16], py[16], pz[16], dist[16];
#pragma unroll
  for (int k=0;k<16;k++){
    int n = k*1024 + t;
    px[k]=xb[n]; py[k]=xb[NN+n]; pz[k]=xb[2*NN+n];
    dist[k]=1e10f;
  }
#pragma unroll
  for (int k=0;k<16;k++){
    asm volatile("" : "+v"(px[k]), "+v"(py[k]), "+v"(pz[k]));
  }
  __shared__ unsigned long long redk[2][16];
  int wid = t >> 6, lane = t & 63;
  float cx = xb[0], cy = xb[NN], cz = xb[2*NN];
  for (int step=0; step<SS; ++step){
    if (t==0){
      float* nx = nxyz + ((size_t)b*SS + step)*3;
      nx[0]=cx; nx[1]=cy; nx[2]=cz;
      float* ox = out + (size_t)b*3*SS;
      ox[step]=cx; ox[SS+step]=cy; ox[2*SS+step]=cz;
    }
    float bv = -1.0f; int bk = 0;
#pragma unroll
    for (int k=0;k<16;k++){
      float dx=fsb(px[k],cx), dy=fsb(py[k],cy), dz=fsb(pz[k],cz);
      float d = fa(fa(fm(dx,dx),fm(dy,dy)),fm(dz,dz));
      float dk = fminf(dist[k], d);
      dist[k]=dk;
      if (dk > bv){ bv=dk; bk=k; }   // strict > keeps earliest k
    }
    int bi = (bk<<10) | t;
    unsigned long long key = ((unsigned long long)__float_as_uint(bv) << 32)
                           | (unsigned)(16384 - bi);
#pragma unroll
    for (int off=1; off<64; off<<=1){
      unsigned long long ok = __shfl_xor(key, off);
      if (ok > key) key = ok;
    }
    int par = step & 1;
    if (lane==0) redk[par][wid] = key;
    __syncthreads();
    unsigned long long k2 = redk[par][lane & 15];
#pragma unroll
    for (int off=1; off<16; off<<=1){
      unsigned long long ok = __shfl_xor(k2, off);
      if (ok > k2) k2 = ok;
    }
    int i = 16384 - (int)(unsigned)(k2 & 0xFFFFFFFFull);
    cx = xb[i]; cy = xb[NN+i]; cz = xb[2*NN+i];
  }
}

// ---------------- grid barrier v3: R8's PROVEN protocol, minus the contention ----------------
// Diff from R8 (which ran to completion, bit-exact): (1) only tid==0 polls the
// flag -- 512 pollers instead of 32768 (R4-validated scale; R8's 64-lane
// polling was the R3 coherence-point pathology and its ~500us cost); (2) the
// spin is BOUNDED (1e6 iters ~ >100ms >> legit ~100us wait): if barrier logic
// is ever wrong the kernel completes with garbage -> finite absmax + counters
// instead of a wedged container (R9/R10 lesson). Arrival path (single
// fetch_add counter + reset-before-release-publish) is byte-identical to R8.
// Flag is monotone 1..6 within a run; fps resets bar[] every replay.
__device__ __forceinline__ void gridbar(unsigned* __restrict__ bar, unsigned phase){
  __syncthreads();
  if (threadIdx.x == 0){
    __builtin_amdgcn_fence(__ATOMIC_RELEASE, "agent");
    unsigned old = __hip_atomic_fetch_add(&bar[0], 1u, __ATOMIC_ACQ_REL, __HIP_MEMORY_SCOPE_AGENT);
    if (old == (unsigned)(NBK-1)){
      __hip_atomic_store(&bar[0], 0u, __ATOMIC_RELAXED, __HIP_MEMORY_SCOPE_AGENT);
      __hip_atomic_store(&bar[1], phase, __ATOMIC_RELEASE, __HIP_MEMORY_SCOPE_AGENT);
    }
    unsigned spins = 0u;
    while (__hip_atomic_load(&bar[1], __ATOMIC_ACQUIRE, __HIP_MEMORY_SCOPE_AGENT) < phase){
      __builtin_amdgcn_s_sleep(4);
      if (++spins > 1000000u) break;   // hang-proof bailout (see header comment)
    }
  }
  __syncthreads();
  __builtin_amdgcn_fence(__ATOMIC_ACQUIRE, "agent");
}

// ---------------- ball query into LDS row (math verbatim R6 ballq) ----------------
__device__ __forceinline__ void ballq_lds(const float* __restrict__ xb,
                                          const float* __restrict__ nx3,
                                          int* __restrict__ grow){
  int lane = threadIdx.x & 63;
  float nx=nx3[0], ny=nx3[1], nz=nx3[2];
  float cn = fa(fa(fm(nx,nx),fm(ny,ny)),fm(nz,nz));
  const float R2 = (float)(0.2*0.2);   // f64 product rounded once to f32
  int cnt = 0; int first_idx = 0;
  for (int base=0; base<NN; base+=64){
    int n = base + lane;
    float x=xb[n], y=xb[NN+n], z=xb[2*NN+n];
    float sq = fa(fa(fm(x,x),fm(y,y)),fm(z,z));      // == old sqn[n], bit-exact
    float dot = fa(fa(fm(nx,x),fm(ny,y)),fm(nz,z));
    float sqd = fsb(fa(cn, sq), fm(2.0f, dot));
    bool inb = !(sqd > R2);
    unsigned long long m = __ballot(inb);
    if (m){
      if (cnt==0) first_idx = base + __builtin_ctzll(m);
      int pre = __popcll(m & ((1ull<<lane)-1ull));
      int slot = cnt + pre;
      if (inb && slot < KK) grow[slot] = n;
      cnt += __popcll(m);
      if (cnt >= KK) break;
    }
  }
  if (cnt < KK && lane >= cnt && lane < KK) grow[lane] = first_idx;
}

// ---------------- per-channel stats butterfly: deterministic f64 tree ----------------
// (summation order validated bit-exact end-to-end in R8: absmax unchanged)
template<int C>
__device__ __forceinline__ void stat_bfly(double v1, double v2, int o, double* __restrict__ redw){
#pragma unroll
  for (int off=1; off<64; off<<=1){ v1 += __shfl_xor(v1, off); v2 += __shfl_xor(v2, off); }
  if ((threadIdx.x & 63) == 0){
    int w = threadIdx.x >> 6;
    redw[(w*C + o)*2 + 0] = v1;
    redw[(w*C + o)*2 + 1] = v2;
  }
}

template<int C>
__device__ __forceinline__ void stat_emit(double* __restrict__ redw, double* __restrict__ ps, int bid){
  __syncthreads();
  int tid = threadIdx.x;
  if (tid < C){
    double t1=0.0, t2=0.0;
#pragma unroll
    for (int w=0; w<4; w++){ t1 += redw[(w*C+tid)*2]; t2 += redw[(w*C+tid)*2+1]; }
    ps[((size_t)tid*NBK + bid)*2 + 0] = t1;
    ps[((size_t)tid*NBK + bid)*2 + 1] = t2;
  }
}

// ---------------- channel reducer: 512 partials -> a/c (same f64 formula as before) ----------------
__device__ __forceinline__ void reduce_one(const double* __restrict__ ps, int ch,
                                           const float* __restrict__ gamma,
                                           const float* __restrict__ beta,
                                           float* __restrict__ ag, float* __restrict__ cg,
                                           double* __restrict__ lds8){
  int tid = threadIdx.x;
  const double* p = ps + (size_t)ch*NBK*2;
  double s1 = p[tid*2]   + p[(tid+256)*2];
  double s2 = p[tid*2+1] + p[(tid+256)*2+1];
#pragma unroll
  for (int off=1; off<64; off<<=1){ s1 += __shfl_xor(s1, off); s2 += __shfl_xor(s2, off); }
  if ((tid & 63) == 0){ lds8[(tid>>6)*2] = s1; lds8[(tid>>6)*2+1] = s2; }
  __syncthreads();
  if (tid == 0){
    double t1=0.0, t2=0.0;
#pragma unroll
    for (int w=0; w<4; w++){ t1 += lds8[w*2]; t2 += lds8[w*2+1]; }
    double n = (double)BB*KK*SS;
    double m = t1/n;
    double var = t2/n - m*m;
    double inv = 1.0/sqrt(var + 1e-5);
    float s = (float)((double)gamma[ch]*inv);
    ag[ch] = s; cg[ch] = (float)((double)beta[ch] - m*(double)s);
  }
}

// ---------------- megakernel v2: register-resident column pipeline ----------------
// Bodies VERBATIM R8 (ran to completion, validated bit-exact). Only gridbar changed.
__global__ __launch_bounds__(256, 2) void mega_kernel(const float* __restrict__ xyz,
                            const float* __restrict__ pts,
                            const float* __restrict__ nxyz,
                            const float* __restrict__ w0g, const float* __restrict__ b0g,
                            const float* __restrict__ g0, const float* __restrict__ be0,
                            const float* __restrict__ w1g, const float* __restrict__ b1g,
                            const float* __restrict__ g1, const float* __restrict__ be1,
                            const float* __restrict__ w2g, const float* __restrict__ b2g,
                            const float* __restrict__ g2, const float* __restrict__ be2,
                            double* __restrict__ ps0, double* __restrict__ ps1, double* __restrict__ ps2,
                            float* __restrict__ st,       // a0,c0,a1,c1,a2,c2
                            float* __restrict__ outf,     // d_out + B*3*S : (B,128,S)
                            unsigned* __restrict__ bar)
{
  const int bid = blockIdx.x, tid = threadIdx.x;
  const int b   = bid >> 6;            // batch
  const int s0  = (bid & 63) * 8;      // s-range start
  const int si  = tid >> 5;            // 0..7
  const int k   = tid & 31;            // 0..31
  const int w   = tid >> 6;

  __shared__ int    gl[8][KK];
  __shared__ double redw[4*128*2];
  __shared__ float  sa[128], sc[128];

  float* ag0 = st;       float* cg0 = st+64;
  float* ag1 = st+128;   float* cg1 = st+192;
  float* ag2 = st+256;   float* cg2 = st+384;

  const float* xb = xyz + (size_t)b*3*NN;
  const float* pb = pts + (size_t)b*3*NN;

  // ---- P0: ball query for the block's 8 (b,s) pairs (2 per wave) ----
  for (int scan=0; scan<2; ++scan){
    int p = 2*w + scan;
    int s = s0 + p;
    ballq_lds(xb, nxyz + ((size_t)b*SS + s)*3, gl[p]);
  }
  __syncthreads();

  // ---- P1: gather in[6]; stats0 from recomputed y0 ----
  const int s = s0 + si;
  const int idx = gl[si][k];
  const float* nx3 = nxyz + ((size_t)b*SS + s)*3;
  float in[6];
  in[0]=pb[idx]; in[1]=pb[NN+idx]; in[2]=pb[2*NN+idx];
  in[3]=xb[idx]-nx3[0]; in[4]=xb[NN+idx]-nx3[1]; in[5]=xb[2*NN+idx]-nx3[2];
  for (int o=0; o<64; ++o){
    float acc = b0g[o];
#pragma unroll
    for (int c=0;c<6;c++) acc += in[c]*w0g[o*6+c];
    double v = (double)acc;
    stat_bfly<64>(v, v*v, o, redw);
  }
  stat_emit<64>(redw, ps0, bid);
  gridbar(bar, 1);
  if (bid < 64) reduce_one(ps0, bid, g0, be0, ag0, cg0, redw);
  gridbar(bar, 2);

  // ---- P3: x0 = relu-bn(y0); stats1 from recomputed y1 ----
  if (tid < 64){
    sa[tid] = __hip_atomic_load(ag0+tid, __ATOMIC_RELAXED, __HIP_MEMORY_SCOPE_AGENT);
    sc[tid] = __hip_atomic_load(cg0+tid, __ATOMIC_RELAXED, __HIP_MEMORY_SCOPE_AGENT);
  }
  __syncthreads();
  float x0[64];
#pragma unroll
  for (int ci=0; ci<64; ++ci){
    float acc = b0g[ci];
#pragma unroll
    for (int c=0;c<6;c++) acc += in[c]*w0g[ci*6+c];
    x0[ci] = fmaxf(fmaf(acc, sa[ci], sc[ci]), 0.0f);
  }
  for (int o=0; o<64; ++o){
    float acc = b1g[o];
#pragma unroll
    for (int ci=0;ci<64;ci++) acc += x0[ci]*w1g[o*64+ci];
    double v = (double)acc;
    stat_bfly<64>(v, v*v, o, redw);
  }
  stat_emit<64>(redw, ps1, bid);
  gridbar(bar, 3);
  if (bid < 64) reduce_one(ps1, bid, g1, be1, ag1, cg1, redw);
  gridbar(bar, 4);

  // ---- P5: x1 = relu-bn(y1); stats2 from recomputed y2 ----
  if (tid < 64){
    sa[tid] = __hip_atomic_load(ag1+tid, __ATOMIC_RELAXED, __HIP_MEMORY_SCOPE_AGENT);
    sc[tid] = __hip_atomic_load(cg1+tid, __ATOMIC_RELAXED, __HIP_MEMORY_SCOPE_AGENT);
  }
  __syncthreads();
  float x1[64];
#pragma unroll
  for (int ci=0; ci<64; ++ci){
    float acc = b1g[ci];
#pragma unroll
    for (int cj=0;cj<64;cj++) acc += x0[cj]*w1g[ci*64+cj];
    x1[ci] = fmaxf(fmaf(acc, sa[ci], sc[ci]), 0.0f);
  }
  for (int o=0; o<128; ++o){
    float acc = b2g[o];
#pragma unroll
    for (int ci=0;ci<64;ci++) acc += x1[ci]*w2g[o*64+ci];
    double v = (double)acc;
    stat_bfly<128>(v, v*v, o, redw);
  }
  stat_emit<128>(redw, ps2, bid);
  gridbar(bar, 5);
  if (bid < 128) reduce_one(ps2, bid, g2, be2, ag2, cg2, redw);
  gridbar(bar, 6);

  // ---- P7: final = max over k of relu-bn(recomputed y2) ----
  if (tid < 128){
    sa[tid] = __hip_atomic_load(ag2+tid, __ATOMIC_RELAXED, __HIP_MEMORY_SCOPE_AGENT);
    sc[tid] = __hip_atomic_load(cg2+tid, __ATOMIC_RELAXED, __HIP_MEMORY_SCOPE_AGENT);
  }
  __syncthreads();
  for (int o=0; o<128; ++o){
    float acc = b2g[o];
#pragma unroll
    for (int ci=0;ci<64;ci++) acc += x1[ci]*w2g[o*64+ci];
    float val = fmaxf(fmaf(acc, sa[o], sc[o]), 0.0f);
#pragma unroll
    for (int off=1; off<32; off<<=1) val = fmaxf(val, __shfl_xor(val, off));
    if (k == 0) outf[((size_t)b*128 + o)*SS + s] = val;
  }
}

extern "C" void kernel_launch(void* const* d_in, const int* in_sizes, int n_in,
                              void* d_out, int out_size, void* d_ws, size_t ws_size,
                              hipStream_t stream)
{
  const float* xyz = (const float*)d_in[0];
  const float* pts = (const float*)d_in[1];
  const float* w0  = (const float*)d_in[2];
  const float* b0  = (const float*)d_in[3];
  const float* g0  = (const float*)d_in[4];
  const float* be0 = (const float*)d_in[5];
  const float* w1  = (const float*)d_in[6];
  const float* b1  = (const float*)d_in[7];
  const float* g1  = (const float*)d_in[8];
  const float* be1 = (const float*)d_in[9];
  const float* w2  = (const float*)d_in[10];
  const float* b2  = (const float*)d_in[11];
  const float* g2  = (const float*)d_in[12];
  const float* be2 = (const float*)d_in[13];
  float* out = (float*)d_out;

  char* ws = (char*)d_ws;
  float*    nxyz = (float*)   (ws + 524288);    // B*S*3 f32 = 49152 B
  float*    st   = (float*)   (ws + 1097728);   // 512 f32 (a/c per layer)
  unsigned* bar  = (unsigned*)(ws + 1132544);   // 256 x u32 (cnt@0, flag@1)
  double*   ps0  = (double*)  (ws + 4194304);   // 64*512*2 f64 = 512 KB
  double*   ps1  = (double*)  (ws + 8388608);   // 64*512*2 f64 = 512 KB
  double*   ps2  = (double*)  (ws + 12582912);  // 128*512*2 f64 = 1 MB
  (void)ws_size; (void)in_sizes; (void)n_in; (void)out_size;

  fps_kernel<<<dim3(BB), dim3(1024), 0, stream>>>(xyz, nxyz, out, bar);
  mega_kernel<<<dim3(NBK), dim3(256), 0, stream>>>(xyz, pts, nxyz,
      w0, b0, g0, be0, w1, b1, g1, be1, w2, b2, g2, be2,
      ps0, ps1, ps2, st, out + BB*3*SS, bar);
}

// Round 12
// 1284.862 us; speedup vs baseline: 1.5412x; 1.4103x over previous
//
#include <hip/hip_runtime.h>
#include <cstdint>
#include <cstddef>

#define BB 8
#define NN 16384
#define SS 512
#define KK 32

__device__ __forceinline__ float fm(float a, float b){ return __fmul_rn(a,b); }
__device__ __forceinline__ float fa(float a, float b){ return __fadd_rn(a,b); }
__device__ __forceinline__ float fsb(float a, float b){ return __fsub_rn(a,b); }

// ---------------- per-point squared norm (numpy order: (x^2+y^2)+z^2) ----------------
__global__ void sqnorm_kernel(const float* __restrict__ xyz, float* __restrict__ sqn){
  int gid = blockIdx.x*blockDim.x + threadIdx.x; // B*N
  int b = gid >> 14; int n = gid & (NN-1);
  const float* xb = xyz + (size_t)b*3*NN;
  float x = xb[n], y = xb[NN+n], z = xb[2*NN+n];
  sqn[gid] = fa(fa(fm(x,x),fm(y,y)),fm(z,z));
}

// ---------------- farthest point sampling: 1 block (1024 thr) per batch ----------------
// Session-final structure (validated at 1282us total, R2). One block per batch:
// R3/R4 proved the cross-block agent-scope barrier floor (~1.4us/step) exceeds
// the single-block step cost; R0/R1 proved packed-f32 and remat-pinning give
// <=2%. The asm identity pins keep the 48 point coords register-resident
// (without them the compiler re-loads all 48 from L2 every one of 512 steps).
// DO NOT change launch config without re-verifying post-timing:
// __launch_bounds__(512,1)-style edits broke graph-replay revalidation before.
__global__ __launch_bounds__(1024, 4) void fps_kernel(const float* __restrict__ xyz,
                                                      float* __restrict__ nxyz,   // ws (B,S,3)
                                                      float* __restrict__ out)    // d_out (B,3,S)
{
  int b = blockIdx.x;
  int t = threadIdx.x;           // 0..1023
  const float* xb = xyz + (size_t)b*3*NN;
  float px[16], py[16], pz[16], dist[16];
#pragma unroll
  for (int k=0;k<16;k++){
    int n = k*1024 + t;
    px[k]=xb[n]; py[k]=xb[NN+n]; pz[k]=xb[2*NN+n];
    dist[k]=1e10f;
  }
  // Pin point coords in registers (block rematerialization-as-reload).
#pragma unroll
  for (int k=0;k<16;k++){
    asm volatile("" : "+v"(px[k]), "+v"(py[k]), "+v"(pz[k]));
  }
  __shared__ unsigned long long redk[2][16];
  int wid = t >> 6, lane = t & 63;
  float cx = xb[0], cy = xb[NN], cz = xb[2*NN];
  for (int step=0; step<SS; ++step){
    if (t==0){
      float* nx = nxyz + ((size_t)b*SS + step)*3;
      nx[0]=cx; nx[1]=cy; nx[2]=cz;
      float* ox = out + (size_t)b*3*SS;
      ox[step]=cx; ox[SS+step]=cy; ox[2*SS+step]=cz;
    }
    float bv = -1.0f; int bk = 0;
#pragma unroll
    for (int k=0;k<16;k++){
      float dx=fsb(px[k],cx), dy=fsb(py[k],cy), dz=fsb(pz[k],cz);
      float d = fa(fa(fm(dx,dx),fm(dy,dy)),fm(dz,dz));
      float dk = fminf(dist[k], d);
      dist[k]=dk;
      // strict > keeps earliest k => smallest index for this thread
      if (dk > bv){ bv=dk; bk=k; }
    }
    int bi = (bk<<10) | t;
    unsigned long long key = ((unsigned long long)__float_as_uint(bv) << 32)
                           | (unsigned)(16384 - bi);
    // wave(64) butterfly max on packed key
#pragma unroll
    for (int off=1; off<64; off<<=1){
      unsigned long long ok = __shfl_xor(key, off);
      if (ok > key) key = ok;
    }
    int par = step & 1;
    if (lane==0) redk[par][wid] = key;
    __syncthreads();
    // every lane reads one of the 16 candidates (4-way same-address broadcast),
    // then 4-stage butterfly within each group of 16 -> all 64 lanes converge
    unsigned long long k2 = redk[par][lane & 15];
#pragma unroll
    for (int off=1; off<16; off<<=1){
      unsigned long long ok = __shfl_xor(k2, off);
      if (ok > k2) k2 = ok;
    }
    int i = 16384 - (int)(unsigned)(k2 & 0xFFFFFFFFull);
    cx = xb[i]; cy = xb[NN+i]; cz = xb[2*NN+i];
  }
}

// ---------------- ball query: 1 wave per centroid, early exit at 32 hits ----------------
__global__ void ballq_kernel(const float* __restrict__ xyz,
                             const float* __restrict__ sqn,
                             const float* __restrict__ nxyz,
                             int* __restrict__ gidx)
{
  int wv = (blockIdx.x * (blockDim.x>>6)) + (threadIdx.x>>6); // B*S waves
  int lane = threadIdx.x & 63;
  int b = wv >> 9; int s = wv & (SS-1);
  const float* nx3 = nxyz + ((size_t)b*SS + s)*3;
  float nx=nx3[0], ny=nx3[1], nz=nx3[2];
  float cn = fa(fa(fm(nx,nx),fm(ny,ny)),fm(nz,nz));
  const float* xb = xyz + (size_t)b*3*NN;
  const float* sb = sqn + (size_t)b*NN;
  const float R2 = (float)(0.2*0.2);   // f64 product rounded once to f32
  int* g = gidx + ((size_t)b*SS + s)*KK;
  int cnt = 0; int first_idx = 0;
  for (int base=0; base<NN; base+=64){
    int n = base + lane;
    float x=xb[n], y=xb[NN+n], z=xb[2*NN+n];
    float dot = fa(fa(fm(nx,x),fm(ny,y)),fm(nz,z));
    float sqd = fsb(fa(cn, sb[n]), fm(2.0f, dot));
    bool inb = !(sqd > R2);
    unsigned long long m = __ballot(inb);
    if (m){
      if (cnt==0) first_idx = base + __builtin_ctzll(m);
      int pre = __popcll(m & ((1ull<<lane)-1ull));
      int slot = cnt + pre;
      if (inb && slot < KK) g[slot] = n;
      cnt += __popcll(m);
      if (cnt >= KK) break;
    }
  }
  if (cnt < KK && lane >= cnt && lane < KK) g[lane] = first_idx;
}

// ---------------- layer 0: gather + concat + conv(6->64) ----------------
__global__ __launch_bounds__(256) void mlp0_kernel(const float* __restrict__ xyz,
                            const float* __restrict__ pts,
                            const float* __restrict__ nxyz,
                            const int* __restrict__ gidx,
                            const float* __restrict__ w,    // (64,6)
                            const float* __restrict__ bias,
                            float* __restrict__ y0)         // (B,64,K,S)
{
  int gid = blockIdx.x*blockDim.x + threadIdx.x;  // B*K*S
  int b = gid / (KK*SS);
  int r = gid % (KK*SS);
  int k = r / SS; int s = r % SS;
  int idx = gidx[((size_t)b*SS + s)*KK + k];
  const float* pb = pts + (size_t)b*3*NN;
  const float* xb = xyz + (size_t)b*3*NN;
  const float* nx3 = nxyz + ((size_t)b*SS + s)*3;
  float in[6];
  in[0]=pb[idx]; in[1]=pb[NN+idx]; in[2]=pb[2*NN+idx];
  in[3]=xb[idx]-nx3[0]; in[4]=xb[NN+idx]-nx3[1]; in[5]=xb[2*NN+idx]-nx3[2];
  float* po = y0 + (size_t)b*64*KK*SS + r;
  for (int o=0;o<64;o++){
    float acc = bias[o];
#pragma unroll
    for (int c=0;c<6;c++) acc += in[c]*w[o*6+c];
    po[(size_t)o*KK*SS] = acc;
  }
}

// ---------------- BN stats, pass 1: per-(channel,batch) partial sums ----------------
// grid = C*8 blocks; block (o, b) reads the contiguous 64KB run y[b][o][:][:]
// with float4 loads; deterministic partial (s1,s2) per block -> psum (no atomics).
__global__ __launch_bounds__(256) void stats_part_kernel(const float* __restrict__ y, int C,
                                                         double* __restrict__ psum)
{
  int o = blockIdx.x >> 3; int b = blockIdx.x & 7;
  int t = threadIdx.x;
  const float4* p = (const float4*)(y + ((size_t)b*C + o)*KK*SS);
  double s1=0.0, s2=0.0;
#pragma unroll
  for (int i=0;i<16;i++){
    float4 v = p[t + i*256];
    double x0=v.x, x1=v.y, x2=v.z, x3=v.w;
    s1 += x0+x1; s1 += x2+x3;
    s2 += x0*x0 + x1*x1;
    s2 += x2*x2 + x3*x3;
  }
#pragma unroll
  for (int off=32; off>=1; off>>=1){
    s1 += __shfl_down(s1, off);
    s2 += __shfl_down(s2, off);
  }
  __shared__ double l1[4], l2[4];
  int wid = t>>6;
  if ((t&63)==0){ l1[wid]=s1; l2[wid]=s2; }
  __syncthreads();
  if (t==0){
    double t1=l1[0]+l1[1]+l1[2]+l1[3];
    double t2=l2[0]+l2[1]+l2[2]+l2[3];
    psum[(o*8+b)*2+0]=t1;
    psum[(o*8+b)*2+1]=t2;
  }
}

// ---------------- BN stats, pass 2: finalize scale/shift ----------------
__global__ void stats_fin_kernel(const double* __restrict__ psum, int C,
                                 const float* __restrict__ gamma,
                                 const float* __restrict__ beta,
                                 float* __restrict__ a, float* __restrict__ c)
{
  int o = threadIdx.x;
  if (o >= C) return;
  double t1=0.0, t2=0.0;
#pragma unroll
  for (int b=0;b<8;b++){ t1 += psum[(o*8+b)*2+0]; t2 += psum[(o*8+b)*2+1]; }
  double n = (double)BB*KK*SS;
  double m = t1/n;
  double var = t2/n - m*m;
  double inv = 1.0/sqrt(var + 1e-5);
  float sc = (float)((double)gamma[o]*inv);
  a[o]=sc; c[o]=(float)((double)beta[o] - m*(double)sc);
}

// ---------------- conv layer: BN+ReLU applied to input on the fly ----------------
template<int CIN, int COUT>
__global__ __launch_bounds__(256) void mlp_kernel(const float* __restrict__ yin,
                            const float* __restrict__ w,
                            const float* __restrict__ bias,
                            const float* __restrict__ a,
                            const float* __restrict__ cc,
                            float* __restrict__ yout)
{
  int gid = blockIdx.x*blockDim.x + threadIdx.x; // B*K*S
  int b = gid / (KK*SS);
  int r = gid % (KK*SS);
  const float* pin = yin + (size_t)b*CIN*KK*SS + r;
  float x[CIN];
#pragma unroll
  for (int ci=0;ci<CIN;ci++) x[ci] = fmaxf(fmaf(pin[(size_t)ci*KK*SS], a[ci], cc[ci]), 0.0f);
  float* po = yout + (size_t)b*COUT*KK*SS + r;
  for (int o=0;o<COUT;o++){
    float acc = bias[o];
#pragma unroll
    for (int ci=0;ci<CIN;ci++) acc += x[ci]*w[o*CIN+ci];
    po[(size_t)o*KK*SS] = acc;
  }
}

// ---------------- final: BN+ReLU+max over K, float4 ----------------
__global__ __launch_bounds__(256) void final_kernel(const float* __restrict__ y2,
                             const float* __restrict__ a,
                             const float* __restrict__ cc,
                             float* __restrict__ out)  // (B,128,S)
{
  int gid = blockIdx.x*blockDim.x + threadIdx.x; // B*128*(S/4)
  int b = gid / (128*128);
  int r = gid % (128*128);
  int o = r >> 7; int s4 = (r & 127);
  const float4* p = (const float4*)(y2 + ((size_t)b*128 + o)*KK*SS) + s4;
  float sc=a[o], sh=cc[o];
  float m0=0.f,m1=0.f,m2=0.f,m3=0.f;  // relu outputs >= 0, 32 values exist
#pragma unroll
  for (int k=0;k<KK;k++){
    float4 v = p[k*(SS/4)];
    m0 = fmaxf(m0, fmaxf(fmaf(v.x, sc, sh), 0.0f));
    m1 = fmaxf(m1, fmaxf(fmaf(v.y, sc, sh), 0.0f));
    m2 = fmaxf(m2, fmaxf(fmaf(v.z, sc, sh), 0.0f));
    m3 = fmaxf(m3, fmaxf(fmaf(v.w, sc, sh), 0.0f));
  }
  float4* po = (float4*)(out + ((size_t)b*128 + o)*SS) + s4;
  *po = make_float4(m0,m1,m2,m3);
}

extern "C" void kernel_launch(void* const* d_in, const int* in_sizes, int n_in,
                              void* d_out, int out_size, void* d_ws, size_t ws_size,
                              hipStream_t stream)
{
  const float* xyz = (const float*)d_in[0];
  const float* pts = (const float*)d_in[1];
  const float* w0  = (const float*)d_in[2];
  const float* b0  = (const float*)d_in[3];
  const float* g0  = (const float*)d_in[4];
  const float* be0 = (const float*)d_in[5];
  const float* w1  = (const float*)d_in[6];
  const float* b1  = (const float*)d_in[7];
  const float* g1  = (const float*)d_in[8];
  const float* be1 = (const float*)d_in[9];
  const float* w2  = (const float*)d_in[10];
  const float* b2  = (const float*)d_in[11];
  const float* g2  = (const float*)d_in[12];
  const float* be2 = (const float*)d_in[13];
  float* out = (float*)d_out;

  char* ws = (char*)d_ws;
  float*  sqn  = (float*) (ws + 0);          // B*N f32          = 524288 B
  float*  nxyz = (float*) (ws + 524288);     // B*S*3 f32        = 49152 B
  int*    gidx = (int*)   (ws + 573440);     // B*S*K i32        = 524288 B
  float*  st   = (float*) (ws + 1097728);    // 512 f32 (a/c per layer)
  double* ps0  = (double*)(ws + 1099776);    // 64*8*2 f64  = 8192 B
  double* ps1  = (double*)(ws + 1107968);    // 64*8*2 f64  = 8192 B
  double* ps2  = (double*)(ws + 1116160);    // 128*8*2 f64 = 16384 B
  float* a0=st,     *c0=st+64;
  float* a1=st+128, *c1=st+192;
  float* a2=st+256, *c2=st+384;
  // y1 at 4MiB (33.5MB), y2 at 40MiB (67MB), y0 at 76MiB (33.5MB; dead before y2 written)
  float* y1 = (float*)(ws + 4194304);
  float* y2 = (float*)(ws + 41943040);
  float* y0 = (float*)(ws + 79691776);
  (void)ws_size; (void)in_sizes; (void)n_in; (void)out_size;

  sqnorm_kernel<<<dim3(512), dim3(256), 0, stream>>>(xyz, sqn);
  fps_kernel<<<dim3(BB), dim3(1024), 0, stream>>>(xyz, nxyz, out);
  ballq_kernel<<<dim3(1024), dim3(256), 0, stream>>>(xyz, sqn, nxyz, gidx);
  mlp0_kernel<<<dim3(512), dim3(256), 0, stream>>>(xyz, pts, nxyz, gidx, w0, b0, y0);
  stats_part_kernel<<<dim3(64*8), dim3(256), 0, stream>>>(y0, 64, ps0);
  stats_fin_kernel<<<dim3(1), dim3(64), 0, stream>>>(ps0, 64, g0, be0, a0, c0);
  mlp_kernel<64,64><<<dim3(512), dim3(256), 0, stream>>>(y0, w1, b1, a0, c0, y1);
  stats_part_kernel<<<dim3(64*8), dim3(256), 0, stream>>>(y1, 64, ps1);
  stats_fin_kernel<<<dim3(1), dim3(64), 0, stream>>>(ps1, 64, g1, be1, a1, c1);
  mlp_kernel<64,128><<<dim3(512), dim3(256), 0, stream>>>(y1, w2, b2, a1, c1, y2);
  stats_part_kernel<<<dim3(128*8), dim3(256), 0, stream>>>(y2, 128, ps2);
  stats_fin_kernel<<<dim3(1), dim3(128), 0, stream>>>(ps2, 128, g2, be2, a2, c2);
  final_kernel<<<dim3(512), dim3(256), 0, stream>>>(y2, a2, c2, out + BB*3*SS);
}